// Round 2
// baseline (3570.359 us; speedup 1.0000x reference)
//
#include <hip/hip_runtime.h>

#define NB 2
#define NN 2048
#define NC 16
#define NFG 15
#define NPAIR (NB * NFG)
#define THREADS 256
#define DETS 100
#define SCORE_TH 0.05f
#define NMS_TH 0.5f
#define BBOX_CLIP 4.135166556742356f
#define IMG_MAX 1023.0f

// -------- Kernel 1: per (image, class) softmax + decode + sort + greedy NMS --------
__global__ __launch_bounds__(THREADS)
void nms_class_kernel(const float* __restrict__ logits,
                      const float* __restrict__ deltas,
                      const float* __restrict__ props,
                      float* __restrict__ sbOut,   // [NPAIR][NN][4] sorted boxes
                      float* __restrict__ sthOut,  // [NPAIR][NN]    sorted theta
                      float* __restrict__ mscOut,  // [NPAIR][NN]    keep ? score : -1
                      float* __restrict__ ubTmp,   // [NPAIR][NN][4] unsorted boxes
                      float* __restrict__ uthTmp)  // [NPAIR][NN]    unsorted theta
{
    const int pair = blockIdx.x;       // 0..29
    const int b    = pair / NFG;
    const int cls  = pair % NFG + 1;   // foreground classes 1..15
    const int tid  = threadIdx.x;

    const float* L = logits + (size_t)b * NN * NC;
    const float* D = deltas + (size_t)b * NN * NC * 5;
    const float* P = props  + (size_t)b * NN * 4;

    __shared__ unsigned long long keys[NN];   // 16 KB
    __shared__ float4 sbl[NN];                // 32 KB sorted boxes
    __shared__ float  sscl[NN];               //  8 KB sorted scores
    __shared__ unsigned char supp[NN];        //  2 KB
    __shared__ unsigned char keepm[NN];       //  2 KB   (total 60 KB)

    // ---- Phase A: softmax score for this class + decode + clip ----
    for (int n = tid; n < NN; n += THREADS) {
        const float* lr = L + n * NC;
        float m = lr[0];
#pragma unroll
        for (int c = 1; c < NC; ++c) m = fmaxf(m, lr[c]);
        float sum = 0.0f, ec = 0.0f;
#pragma unroll
        for (int c = 0; c < NC; ++c) {
            float e = expf(__fsub_rn(lr[c], m));
            sum = __fadd_rn(sum, e);
            if (c == cls) ec = e;
        }
        float sc = __fdiv_rn(ec, sum);

        float px1 = P[n*4+0], py1 = P[n*4+1], px2 = P[n*4+2], py2 = P[n*4+3];
        float w  = __fadd_rn(__fsub_rn(px2, px1), 1.0f);
        float h  = __fadd_rn(__fsub_rn(py2, py1), 1.0f);
        float cx = __fadd_rn(px1, __fmul_rn(0.5f, w));
        float cy = __fadd_rn(py1, __fmul_rn(0.5f, h));

        const float* dd = D + n * NC * 5 + cls * 5;
        float dx = __fdiv_rn(dd[0], 10.0f);
        float dy = __fdiv_rn(dd[1], 10.0f);
        float dw = fminf(__fdiv_rn(dd[2], 5.0f), BBOX_CLIP);
        float dh = fminf(__fdiv_rn(dd[3], 5.0f), BBOX_CLIP);
        float th = dd[4];

        float pcx = __fadd_rn(__fmul_rn(dx, w), cx);
        float pcy = __fadd_rn(__fmul_rn(dy, h), cy);
        float pw  = __fmul_rn(expf(dw), w);
        float ph  = __fmul_rn(expf(dh), h);

        float bx1 = __fsub_rn(pcx, __fmul_rn(0.5f, pw));
        float by1 = __fsub_rn(pcy, __fmul_rn(0.5f, ph));
        float bx2 = __fsub_rn(__fadd_rn(pcx, __fmul_rn(0.5f, pw)), 1.0f);
        float by2 = __fsub_rn(__fadd_rn(pcy, __fmul_rn(0.5f, ph)), 1.0f);

        bx1 = fminf(fmaxf(bx1, 0.0f), IMG_MAX);
        by1 = fminf(fmaxf(by1, 0.0f), IMG_MAX);
        bx2 = fminf(fmaxf(bx2, 0.0f), IMG_MAX);
        by2 = fminf(fmaxf(by2, 0.0f), IMG_MAX);

        ((float4*)ubTmp)[(size_t)pair * NN + n] = make_float4(bx1, by1, bx2, by2);
        uthTmp[(size_t)pair * NN + n] = th;
        // stable-descending key: score bits (positive -> order-preserving) | inverted index
        keys[n] = ((unsigned long long)__float_as_uint(sc) << 32)
                | (unsigned)(NN - 1 - n);
    }

    // ---- bitonic sort, descending (mirrors stable argsort(-scores)) ----
    for (unsigned k = 2; k <= NN; k <<= 1) {
        for (unsigned j = k >> 1; j > 0; j >>= 1) {
            __syncthreads();
            for (unsigned i = tid; i < NN; i += THREADS) {
                unsigned ixj = i ^ j;
                if (ixj > i) {
                    unsigned long long a = keys[i], c = keys[ixj];
                    bool sw = ((i & k) == 0) ? (a < c) : (a > c);
                    if (sw) { keys[i] = c; keys[ixj] = a; }
                }
            }
        }
    }
    __syncthreads();

    // ---- gather into sorted order ----
    for (int n = tid; n < NN; n += THREADS) {
        unsigned long long key = keys[n];
        int orig = NN - 1 - (int)(key & 0xFFFFFFFFull);
        float sc = __uint_as_float((unsigned)(key >> 32));
        float4 bx = ((const float4*)ubTmp)[(size_t)pair * NN + orig];
        sscl[n] = sc;
        sbl[n]  = bx;
        ((float4*)sbOut)[(size_t)pair * NN + n] = bx;
        sthOut[(size_t)pair * NN + n] = uthTmp[(size_t)pair * NN + orig];
        supp[n]  = 0;
        keepm[n] = 0;
    }
    __syncthreads();

    // ---- greedy NMS: serial over sorted i, parallel suppression row ----
    for (int i = 0; i < NN; ++i) {
        // uniform decision across block (reads LDS only)
        if (!(sscl[i] > SCORE_TH) || supp[i]) continue;
        if (tid == 0) keepm[i] = 1;
        float4 a = sbl[i];
        float aarea = __fmul_rn(__fadd_rn(__fsub_rn(a.z, a.x), 1.0f),
                                __fadd_rn(__fsub_rn(a.w, a.y), 1.0f));
        for (int j = tid; j < NN; j += THREADS) {
            float4 c = sbl[j];
            float xx1 = fmaxf(a.x, c.x);
            float yy1 = fmaxf(a.y, c.y);
            float xx2 = fminf(a.z, c.z);
            float yy2 = fminf(a.w, c.w);
            float iw = fmaxf(__fadd_rn(__fsub_rn(xx2, xx1), 1.0f), 0.0f);
            float ih = fmaxf(__fadd_rn(__fsub_rn(yy2, yy1), 1.0f), 0.0f);
            float inter = __fmul_rn(iw, ih);
            float carea = __fmul_rn(__fadd_rn(__fsub_rn(c.z, c.x), 1.0f),
                                    __fadd_rn(__fsub_rn(c.w, c.y), 1.0f));
            float denom = __fsub_rn(__fadd_rn(aarea, carea), inter);
            float iou = __fdiv_rn(inter, denom);
            if (iou > NMS_TH) supp[j] = 1;
        }
        __syncthreads();
    }

    // ---- masked score for the top-k stage ----
    for (int n = tid; n < NN; n += THREADS) {
        mscOut[(size_t)pair * NN + n] = keepm[n] ? sscl[n] : -1.0f;
    }
}

// -------- Kernel 2: per-image top-100 + output assembly --------
__global__ __launch_bounds__(THREADS)
void topk_kernel(const float* __restrict__ sb,
                 const float* __restrict__ sth,
                 const float* __restrict__ msc,
                 float* __restrict__ out)
{
    const int b   = blockIdx.x;
    const int tid = threadIdx.x;
    const int M   = NFG * NN;   // 30720 candidates per image

    __shared__ unsigned int consumed[M / 32];        // 3840 B
    __shared__ unsigned long long red[THREADS];

    for (int i = tid; i < M / 32; i += THREADS) consumed[i] = 0;
    __syncthreads();

    const float* mscb = msc + (size_t)b * M;

    for (int k = 0; k < DETS; ++k) {
        unsigned long long best = 0;
        for (int f = tid; f < M; f += THREADS) {
            if (consumed[f >> 5] & (1u << (f & 31))) continue;
            unsigned vb = __float_as_uint(mscb[f]);
            vb = (vb & 0x80000000u) ? ~vb : (vb | 0x80000000u);  // orderable
            unsigned long long key = ((unsigned long long)vb << 32)
                                   | (unsigned)(M - 1 - f);       // ties -> lowest f
            if (key > best) best = key;
        }
        red[tid] = best;
        __syncthreads();
        for (int s = THREADS / 2; s > 0; s >>= 1) {
            if (tid < s && red[tid + s] > red[tid]) red[tid] = red[tid + s];
            __syncthreads();
        }
        unsigned long long win = red[0];
        int f = M - 1 - (int)(win & 0xFFFFFFFFull);
        unsigned vb = (unsigned)(win >> 32);
        float val = __uint_as_float((vb & 0x80000000u) ? (vb & 0x7FFFFFFFu) : ~vb);
        bool vld = val > 0.0f;

        if (tid == 0) {
            consumed[f >> 5] |= (1u << (f & 31));
            int o = b * DETS + k;
            float4 bx = make_float4(0.f, 0.f, 0.f, 0.f);
            float th = 0.f, lab = 0.f;
            if (vld) {
                bx  = ((const float4*)sb)[(size_t)b * M + f];
                th  = sth[(size_t)b * M + f];
                lab = (float)(f / NN + 1);
            }
            // output layout: boxes[2][100][4] | scores[2][100] | theta[2][100]
            //                | labels[2][100] | valid[2][100]   (all as f32)
            out[o * 4 + 0] = bx.x;
            out[o * 4 + 1] = bx.y;
            out[o * 4 + 2] = bx.z;
            out[o * 4 + 3] = bx.w;
            out[NB * DETS * 4 + o] = vld ? val : 0.0f;
            out[NB * DETS * 5 + o] = th;
            out[NB * DETS * 6 + o] = lab;
            out[NB * DETS * 7 + o] = vld ? 1.0f : 0.0f;
        }
        __syncthreads();
    }
}

extern "C" void kernel_launch(void* const* d_in, const int* in_sizes, int n_in,
                              void* d_out, int out_size, void* d_ws, size_t ws_size,
                              hipStream_t stream) {
    const float* logits = (const float*)d_in[0];   // [2,2048,16]
    const float* deltas = (const float*)d_in[1];   // [2,2048,80]
    const float* props  = (const float*)d_in[2];   // [2,2048,4]
    float* out = (float*)d_out;                    // 1600 floats
    float* ws  = (float*)d_ws;

    float* sbOut  = ws;                                  // NPAIR*NN*4
    float* sthOut = sbOut  + (size_t)NPAIR * NN * 4;     // NPAIR*NN
    float* mscOut = sthOut + (size_t)NPAIR * NN;         // NPAIR*NN
    float* ubTmp  = mscOut + (size_t)NPAIR * NN;         // NPAIR*NN*4
    float* uthTmp = ubTmp  + (size_t)NPAIR * NN * 4;     // NPAIR*NN

    hipLaunchKernelGGL(nms_class_kernel, dim3(NPAIR), dim3(THREADS), 0, stream,
                       logits, deltas, props, sbOut, sthOut, mscOut, ubTmp, uthTmp);
    hipLaunchKernelGGL(topk_kernel, dim3(NB), dim3(THREADS), 0, stream,
                       sbOut, sthOut, mscOut, out);
}

// Round 4
// 523.791 us; speedup vs baseline: 6.8164x; 6.8164x over previous
//
#include <hip/hip_runtime.h>

#define NB 2
#define NN 2048
#define NC 16
#define NFG 15
#define NPAIR (NB * NFG)
#define THREADS 256
#define DETS 100
#define SCORE_TH 0.05f
#define NMS_TH 0.5f
#define BBOX_CLIP 4.135166556742356f
#define IMG_MAX 1023.0f

// -------- Kernel 1: per (image,class) softmax + decode + sort + NMS + top-100 compaction ----
__global__ __launch_bounds__(THREADS)
void nms_class_kernel(const float* __restrict__ logits,
                      const float* __restrict__ deltas,
                      const float* __restrict__ props,
                      float* __restrict__ ubTmp,   // [NPAIR][NN][4] unsorted boxes
                      float* __restrict__ uthTmp,  // [NPAIR][NN]    unsorted theta
                      float* __restrict__ cScore,  // [NPAIR][DETS]  compact scores (-1 pad)
                      float* __restrict__ cBox,    // [NPAIR][DETS][4]
                      float* __restrict__ cTheta)  // [NPAIR][DETS]
{
    const int pair = blockIdx.x;       // 0..29
    const int b    = pair / NFG;
    const int cls  = pair % NFG + 1;   // foreground classes 1..15
    const int tid  = threadIdx.x;

    const float* L = logits + (size_t)b * NN * NC;
    const float* D = deltas + (size_t)b * NN * NC * 5;
    const float* P = props  + (size_t)b * NN * 4;

    __shared__ unsigned long long keys[NN];        // 16 KB (kept intact after sort)
    __shared__ float4 sbl[NN];                     // 32 KB sorted boxes
    __shared__ float  sscl[NN];                    //  8 KB sorted scores
    __shared__ unsigned long long validW[NN / 64]; // 256 B  valid bitmask
    __shared__ int keptPos[DETS];
    __shared__ int keptCount;

    // ---- Phase A: softmax score for this class + decode + clip ----
    for (int n = tid; n < NN; n += THREADS) {
        const float* lr = L + n * NC;
        float m = lr[0];
#pragma unroll
        for (int c = 1; c < NC; ++c) m = fmaxf(m, lr[c]);
        float sum = 0.0f, ec = 0.0f;
#pragma unroll
        for (int c = 0; c < NC; ++c) {
            float e = expf(__fsub_rn(lr[c], m));
            sum = __fadd_rn(sum, e);
            if (c == cls) ec = e;
        }
        float sc = __fdiv_rn(ec, sum);

        float px1 = P[n*4+0], py1 = P[n*4+1], px2 = P[n*4+2], py2 = P[n*4+3];
        float w  = __fadd_rn(__fsub_rn(px2, px1), 1.0f);
        float h  = __fadd_rn(__fsub_rn(py2, py1), 1.0f);
        float cx = __fadd_rn(px1, __fmul_rn(0.5f, w));
        float cy = __fadd_rn(py1, __fmul_rn(0.5f, h));

        const float* dd = D + n * NC * 5 + cls * 5;
        float dx = __fdiv_rn(dd[0], 10.0f);
        float dy = __fdiv_rn(dd[1], 10.0f);
        float dw = fminf(__fdiv_rn(dd[2], 5.0f), BBOX_CLIP);
        float dh = fminf(__fdiv_rn(dd[3], 5.0f), BBOX_CLIP);
        float th = dd[4];

        float pcx = __fadd_rn(__fmul_rn(dx, w), cx);
        float pcy = __fadd_rn(__fmul_rn(dy, h), cy);
        float pw  = __fmul_rn(expf(dw), w);
        float ph  = __fmul_rn(expf(dh), h);

        float bx1 = __fsub_rn(pcx, __fmul_rn(0.5f, pw));
        float by1 = __fsub_rn(pcy, __fmul_rn(0.5f, ph));
        float bx2 = __fsub_rn(__fadd_rn(pcx, __fmul_rn(0.5f, pw)), 1.0f);
        float by2 = __fsub_rn(__fadd_rn(pcy, __fmul_rn(0.5f, ph)), 1.0f);

        bx1 = fminf(fmaxf(bx1, 0.0f), IMG_MAX);
        by1 = fminf(fmaxf(by1, 0.0f), IMG_MAX);
        bx2 = fminf(fmaxf(bx2, 0.0f), IMG_MAX);
        by2 = fminf(fmaxf(by2, 0.0f), IMG_MAX);

        ((float4*)ubTmp)[(size_t)pair * NN + n] = make_float4(bx1, by1, bx2, by2);
        uthTmp[(size_t)pair * NN + n] = th;
        // stable-descending key: score bits (positive -> order-preserving) | inverted index
        keys[n] = ((unsigned long long)__float_as_uint(sc) << 32)
                | (unsigned)(NN - 1 - n);
    }

    // ---- bitonic sort, descending (mirrors stable argsort(-scores)) ----
    for (unsigned k = 2; k <= NN; k <<= 1) {
        for (unsigned j = k >> 1; j > 0; j >>= 1) {
            __syncthreads();
            for (unsigned i = tid; i < NN; i += THREADS) {
                unsigned ixj = i ^ j;
                if (ixj > i) {
                    unsigned long long a = keys[i], c = keys[ixj];
                    bool sw = ((i & k) == 0) ? (a < c) : (a > c);
                    if (sw) { keys[i] = c; keys[ixj] = a; }
                }
            }
        }
    }
    __syncthreads();

    // ---- gather into sorted order + build valid bitmask via ballot ----
    for (int n = tid; n < NN; n += THREADS) {
        unsigned long long key = keys[n];
        int orig = NN - 1 - (int)(key & 0xFFFFFFFFull);
        float sc = __uint_as_float((unsigned)(key >> 32));
        sscl[n] = sc;
        sbl[n]  = ((const float4*)ubTmp)[(size_t)pair * NN + orig];
        unsigned long long bm = __ballot(sc > SCORE_TH);
        if ((tid & 63) == 0) validW[n >> 6] = bm;   // n strided by 256: word-aligned per wave
    }
    __syncthreads();

    // ---- single-wave greedy NMS: bitmasks in registers, early stop at DETS kept ----
    if (tid < 64) {
        const unsigned lane = tid;
        unsigned suppw  = 0;                                  // bits [lane*32, lane*32+32)
        unsigned validw = ((const unsigned*)validW)[lane];
        int kept = 0;
        for (int i = 0; i < NN && kept < DETS; ++i) {
            const int w = i >> 5, bit = i & 31;
            unsigned vw = (unsigned)__shfl((int)validw, w);
            unsigned sw = (unsigned)__shfl((int)suppw,  w);
            if (((vw >> bit) & 1u) && !((sw >> bit) & 1u)) {
                if (lane == 0) keptPos[kept] = i;
                ++kept;
                float4 a = sbl[i];
                float aarea = __fmul_rn(__fadd_rn(__fsub_rn(a.z, a.x), 1.0f),
                                        __fadd_rn(__fsub_rn(a.w, a.y), 1.0f));
                for (int t = 0; t < NN / 64; ++t) {
                    int j = t * 64 + (int)lane;
                    float4 c = sbl[j];
                    float xx1 = fmaxf(a.x, c.x);
                    float yy1 = fmaxf(a.y, c.y);
                    float xx2 = fminf(a.z, c.z);
                    float yy2 = fminf(a.w, c.w);
                    float iw = fmaxf(__fadd_rn(__fsub_rn(xx2, xx1), 1.0f), 0.0f);
                    float ih = fmaxf(__fadd_rn(__fsub_rn(yy2, yy1), 1.0f), 0.0f);
                    float inter = __fmul_rn(iw, ih);
                    float carea = __fmul_rn(__fadd_rn(__fsub_rn(c.z, c.x), 1.0f),
                                            __fadd_rn(__fsub_rn(c.w, c.y), 1.0f));
                    float denom = __fsub_rn(__fadd_rn(aarea, carea), inter);
                    float iou = __fdiv_rn(inter, denom);
                    unsigned long long bm = __ballot(iou > NMS_TH);
                    if (lane == (unsigned)(2 * t))     suppw |= (unsigned)bm;
                    if (lane == (unsigned)(2 * t + 1)) suppw |= (unsigned)(bm >> 32);
                }
            }
        }
        if (lane == 0) keptCount = kept;
    }
    __syncthreads();

    // ---- compact first <=100 kept entries (exact per-pair top-100) ----
    if (tid < DETS) {
        float sc = -1.0f, th = 0.0f;
        float4 bx = make_float4(0.f, 0.f, 0.f, 0.f);
        if (tid < keptCount) {
            int p = keptPos[tid];
            sc = sscl[p];
            bx = sbl[p];
            int orig = NN - 1 - (int)(keys[p] & 0xFFFFFFFFull);
            th = uthTmp[(size_t)pair * NN + orig];
        }
        int g = pair * DETS + tid;
        cScore[g] = sc;
        cTheta[g] = th;
        ((float4*)cBox)[g] = bx;
    }
}

// -------- Kernel 2: per-image top-100 over 1500 compacted candidates (LDS bitonic) ----
#define K2SZ 2048
__global__ __launch_bounds__(THREADS)
void topk_kernel(const float* __restrict__ cScore,
                 const float* __restrict__ cBox,
                 const float* __restrict__ cTheta,
                 float* __restrict__ out)
{
    const int b   = blockIdx.x;
    const int tid = threadIdx.x;
    const int M   = NFG * DETS;   // 1500 candidates per image

    __shared__ unsigned long long keys[K2SZ];   // 16 KB

    for (int t = tid; t < K2SZ; t += THREADS) {
        unsigned long long key = 0ull;          // padding sorts last
        if (t < M) {
            float sc = cScore[(size_t)b * M + t];
            unsigned vb = __float_as_uint(sc);
            vb = (vb & 0x80000000u) ? ~vb : (vb | 0x80000000u);  // orderable
            // low bits: ties -> lower (class, slot) == lower reference flat index
            key = ((unsigned long long)vb << 32) | (unsigned)(K2SZ - 1 - t);
        }
        keys[t] = key;
    }

    for (unsigned k = 2; k <= K2SZ; k <<= 1) {
        for (unsigned j = k >> 1; j > 0; j >>= 1) {
            __syncthreads();
            for (unsigned i = tid; i < K2SZ; i += THREADS) {
                unsigned ixj = i ^ j;
                if (ixj > i) {
                    unsigned long long a = keys[i], c = keys[ixj];
                    bool sw = ((i & k) == 0) ? (a < c) : (a > c);
                    if (sw) { keys[i] = c; keys[ixj] = a; }
                }
            }
        }
    }
    __syncthreads();

    if (tid < DETS) {
        unsigned long long key = keys[tid];
        unsigned vb = (unsigned)(key >> 32);
        float val = __uint_as_float((vb & 0x80000000u) ? (vb & 0x7FFFFFFFu) : ~vb);
        bool vld = val > 0.0f;    // padding decodes to NaN -> false
        float4 bx = make_float4(0.f, 0.f, 0.f, 0.f);
        float th = 0.f, lab = 0.f, scv = 0.f;
        if (vld) {
            int slot = K2SZ - 1 - (int)(key & 0xFFFFFFFFull);  // clsfg*DETS + cidx
            size_t g = (size_t)b * M + slot;
            bx  = ((const float4*)cBox)[g];
            th  = cTheta[g];
            lab = (float)(slot / DETS + 1);
            scv = val;
        }
        int o = b * DETS + tid;
        // output layout: boxes[2][100][4] | scores[2][100] | theta[2][100]
        //                | labels[2][100] | valid[2][100]   (all as f32)
        out[o * 4 + 0] = bx.x;
        out[o * 4 + 1] = bx.y;
        out[o * 4 + 2] = bx.z;
        out[o * 4 + 3] = bx.w;
        out[NB * DETS * 4 + o] = scv;
        out[NB * DETS * 5 + o] = th;
        out[NB * DETS * 6 + o] = lab;
        out[NB * DETS * 7 + o] = vld ? 1.0f : 0.0f;
    }
}

extern "C" void kernel_launch(void* const* d_in, const int* in_sizes, int n_in,
                              void* d_out, int out_size, void* d_ws, size_t ws_size,
                              hipStream_t stream) {
    const float* logits = (const float*)d_in[0];   // [2,2048,16]
    const float* deltas = (const float*)d_in[1];   // [2,2048,80]
    const float* props  = (const float*)d_in[2];   // [2,2048,4]
    float* out = (float*)d_out;                    // 1600 floats
    float* ws  = (float*)d_ws;

    float* ubTmp  = ws;                                   // NPAIR*NN*4
    float* uthTmp = ubTmp  + (size_t)NPAIR * NN * 4;      // NPAIR*NN
    float* cScore = uthTmp + (size_t)NPAIR * NN;          // NPAIR*DETS
    float* cBox   = cScore + (size_t)NPAIR * DETS;        // NPAIR*DETS*4 (16B-aligned)
    float* cTheta = cBox   + (size_t)NPAIR * DETS * 4;    // NPAIR*DETS

    hipLaunchKernelGGL(nms_class_kernel, dim3(NPAIR), dim3(THREADS), 0, stream,
                       logits, deltas, props, ubTmp, uthTmp, cScore, cBox, cTheta);
    hipLaunchKernelGGL(topk_kernel, dim3(NB), dim3(THREADS), 0, stream,
                       cScore, cBox, cTheta, out);
}

// Round 5
// 288.347 us; speedup vs baseline: 12.3822x; 1.8165x over previous
//
#include <hip/hip_runtime.h>

#define NB 2
#define NN 2048
#define NC 16
#define NFG 15
#define NPAIR (NB * NFG)
#define DETS 100
#define SCORE_TH 0.05f
#define NMS_TH 0.5f
#define BBOX_CLIP 4.135166556742356f
#define IMG_MAX 1023.0f

// -------- Kernel A: parallel softmax + decode for all (b, n, cls) --------
// one thread per (b, n); writes class-major arrays
__global__ __launch_bounds__(64)
void decode_kernel(const float* __restrict__ logits,
                   const float* __restrict__ deltas,
                   const float* __restrict__ props,
                   float* __restrict__ scoreAll,  // [NPAIR][NN]
                   float* __restrict__ boxAll,    // [NPAIR][NN][4]
                   float* __restrict__ thetaAll)  // [NPAIR][NN]
{
    const int g = blockIdx.x * 64 + threadIdx.x;   // 0..4095
    const int b = g >> 11;
    const int n = g & (NN - 1);

    // logits row (64B, coalesced float4)
    const float* lr = logits + (size_t)(b * NN + n) * NC;
    float l[NC];
#pragma unroll
    for (int t = 0; t < NC / 4; ++t) {
        float4 v = ((const float4*)lr)[t];
        l[4*t+0] = v.x; l[4*t+1] = v.y; l[4*t+2] = v.z; l[4*t+3] = v.w;
    }
    float m = l[0];
#pragma unroll
    for (int c = 1; c < NC; ++c) m = fmaxf(m, l[c]);
    float ex[NC];
    float sum = 0.0f;
#pragma unroll
    for (int c = 0; c < NC; ++c) {
        ex[c] = expf(__fsub_rn(l[c], m));
        sum = __fadd_rn(sum, ex[c]);
    }

    // proposal box
    float4 pv = ((const float4*)props)[(size_t)b * NN + n];
    float w  = __fadd_rn(__fsub_rn(pv.z, pv.x), 1.0f);
    float h  = __fadd_rn(__fsub_rn(pv.w, pv.y), 1.0f);
    float cx = __fadd_rn(pv.x, __fmul_rn(0.5f, w));
    float cy = __fadd_rn(pv.y, __fmul_rn(0.5f, h));

    // delta row (320B, 20x float4, coalesced-ish)
    const float* drp = deltas + (size_t)(b * NN + n) * NC * 5;
    float dr[NC * 5];
#pragma unroll
    for (int t = 0; t < NC * 5 / 4; ++t) {
        float4 v = ((const float4*)drp)[t];
        dr[4*t+0] = v.x; dr[4*t+1] = v.y; dr[4*t+2] = v.z; dr[4*t+3] = v.w;
    }

#pragma unroll
    for (int cls = 1; cls < NC; ++cls) {
        float dx = __fdiv_rn(dr[cls*5+0], 10.0f);
        float dy = __fdiv_rn(dr[cls*5+1], 10.0f);
        float dw = fminf(__fdiv_rn(dr[cls*5+2], 5.0f), BBOX_CLIP);
        float dh = fminf(__fdiv_rn(dr[cls*5+3], 5.0f), BBOX_CLIP);
        float th = dr[cls*5+4];

        float pcx = __fadd_rn(__fmul_rn(dx, w), cx);
        float pcy = __fadd_rn(__fmul_rn(dy, h), cy);
        float pw  = __fmul_rn(expf(dw), w);
        float ph  = __fmul_rn(expf(dh), h);

        float bx1 = __fsub_rn(pcx, __fmul_rn(0.5f, pw));
        float by1 = __fsub_rn(pcy, __fmul_rn(0.5f, ph));
        float bx2 = __fsub_rn(__fadd_rn(pcx, __fmul_rn(0.5f, pw)), 1.0f);
        float by2 = __fsub_rn(__fadd_rn(pcy, __fmul_rn(0.5f, ph)), 1.0f);

        bx1 = fminf(fmaxf(bx1, 0.0f), IMG_MAX);
        by1 = fminf(fmaxf(by1, 0.0f), IMG_MAX);
        bx2 = fminf(fmaxf(bx2, 0.0f), IMG_MAX);
        by2 = fminf(fmaxf(by2, 0.0f), IMG_MAX);

        size_t idx = (size_t)(b * NFG + cls - 1) * NN + n;
        scoreAll[idx] = __fdiv_rn(ex[cls], sum);
        ((float4*)boxAll)[idx] = make_float4(bx1, by1, bx2, by2);
        thetaAll[idx] = th;
    }
}

// -------- Kernel B: per (image,class) sort + register-mask NMS + top-100 compaction ----
#define BTHREADS 512
__global__ __launch_bounds__(BTHREADS)
void nms_kernel(const float* __restrict__ scoreAll,
                const float* __restrict__ boxAll,
                const float* __restrict__ thetaAll,
                float* __restrict__ cScore,  // [NPAIR][DETS] (-1 pad)
                float* __restrict__ cBox,    // [NPAIR][DETS][4]
                float* __restrict__ cTheta)  // [NPAIR][DETS]
{
    const int pair = blockIdx.x;
    const int tid  = threadIdx.x;

    __shared__ unsigned long long keys[NN];        // 16 KB (intact after sort)
    __shared__ float4 sbl[NN];                     // 32 KB sorted boxes
    __shared__ unsigned long long validW[NN / 64]; // 256 B
    __shared__ int keptPos[DETS];
    __shared__ int keptCount;

    const float* S = scoreAll + (size_t)pair * NN;

    for (int n = tid; n < NN; n += BTHREADS) {
        float sc = S[n];
        keys[n] = ((unsigned long long)__float_as_uint(sc) << 32)
                | (unsigned)(NN - 1 - n);
    }

    // bitonic sort, descending (stable argsort(-scores))
    for (unsigned k = 2; k <= NN; k <<= 1) {
        for (unsigned j = k >> 1; j > 0; j >>= 1) {
            __syncthreads();
            for (unsigned i = tid; i < NN; i += BTHREADS) {
                unsigned ixj = i ^ j;
                if (ixj > i) {
                    unsigned long long a = keys[i], c = keys[ixj];
                    bool sw = ((i & k) == 0) ? (a < c) : (a > c);
                    if (sw) { keys[i] = c; keys[ixj] = a; }
                }
            }
        }
    }
    __syncthreads();

    // gather sorted boxes + valid bitmask (valid = prefix, scores sorted desc)
    for (int n = tid; n < NN; n += BTHREADS) {
        unsigned long long key = keys[n];
        int orig = NN - 1 - (int)(key & 0xFFFFFFFFull);
        sbl[n] = ((const float4*)boxAll)[(size_t)pair * NN + orig];
        float sc = __uint_as_float((unsigned)(key >> 32));
        unsigned long long bm = __ballot(sc > SCORE_TH);
        if ((tid & 63) == 0) validW[n >> 6] = bm;
    }
    __syncthreads();

    // single-wave NMS: remaining-candidate bitmask in registers, ffs jump to next keep
    if (tid < 64) {
        const int lane = tid;
        unsigned rem = ((const unsigned*)validW)[lane];   // bits [lane*32, lane*32+32)

        int cnt = __popc(rem);
#pragma unroll
        for (int o = 32; o >= 1; o >>= 1) cnt += __shfl_xor(cnt, o);
        const int nChunks = (cnt + 63) >> 6;              // valid is a prefix

        float4 rb[32];                                    // lane's boxes: j = t*64 + lane
#pragma unroll
        for (int t = 0; t < 32; ++t) rb[t] = sbl[t * 64 + lane];

        int kept = 0;
        while (kept < DETS) {
            unsigned long long has = __ballot(rem != 0u);
            if (has == 0ull) break;
            int fl  = (int)__builtin_ctzll(has);
            unsigned w = (unsigned)__shfl((int)rem, fl);
            int bit = (int)__builtin_ctz(w);
            int i   = (fl << 5) + bit;                    // next keep (always valid+unsupp)
            if (lane == 0) keptPos[kept] = i;
            ++kept;

            float4 a = sbl[i];                            // LDS broadcast
            float aarea = __fmul_rn(__fadd_rn(__fsub_rn(a.z, a.x), 1.0f),
                                    __fadd_rn(__fsub_rn(a.w, a.y), 1.0f));
#pragma unroll
            for (int t = 0; t < 32; ++t) {
                if (t < nChunks) {
                    float4 c = rb[t];
                    float xx1 = fmaxf(a.x, c.x);
                    float yy1 = fmaxf(a.y, c.y);
                    float xx2 = fminf(a.z, c.z);
                    float yy2 = fminf(a.w, c.w);
                    float iw = fmaxf(__fadd_rn(__fsub_rn(xx2, xx1), 1.0f), 0.0f);
                    float ih = fmaxf(__fadd_rn(__fsub_rn(yy2, yy1), 1.0f), 0.0f);
                    float inter = __fmul_rn(iw, ih);
                    float carea = __fmul_rn(__fadd_rn(__fsub_rn(c.z, c.x), 1.0f),
                                            __fadd_rn(__fsub_rn(c.w, c.y), 1.0f));
                    float denom = __fsub_rn(__fadd_rn(aarea, carea), inter);
                    float iou = __fdiv_rn(inter, denom);
                    unsigned long long bm = __ballot(iou > NMS_TH);
                    if ((lane >> 1) == t)
                        rem &= ~((lane & 1) ? (unsigned)(bm >> 32) : (unsigned)bm);
                }
            }
        }
        if (lane == 0) keptCount = kept;
    }
    __syncthreads();

    // compact first <=100 kept (exact per-pair top-100 under top_k order)
    if (tid < DETS) {
        float sc = -1.0f, th = 0.0f;
        float4 bx = make_float4(0.f, 0.f, 0.f, 0.f);
        if (tid < keptCount) {
            int p = keptPos[tid];
            unsigned long long key = keys[p];
            sc = __uint_as_float((unsigned)(key >> 32));
            bx = sbl[p];
            int orig = NN - 1 - (int)(key & 0xFFFFFFFFull);
            th = thetaAll[(size_t)pair * NN + orig];
        }
        int g = pair * DETS + tid;
        cScore[g] = sc;
        cTheta[g] = th;
        ((float4*)cBox)[g] = bx;
    }
}

// -------- Kernel C: per-image top-100 over 1500 compacted candidates --------
#define K2SZ 2048
__global__ __launch_bounds__(BTHREADS)
void topk_kernel(const float* __restrict__ cScore,
                 const float* __restrict__ cBox,
                 const float* __restrict__ cTheta,
                 float* __restrict__ out)
{
    const int b   = blockIdx.x;
    const int tid = threadIdx.x;
    const int M   = NFG * DETS;   // 1500

    __shared__ unsigned long long keys[K2SZ];   // 16 KB

    for (int t = tid; t < K2SZ; t += BTHREADS) {
        unsigned long long key = 0ull;          // padding sorts last
        if (t < M) {
            float sc = cScore[(size_t)b * M + t];
            unsigned vb = __float_as_uint(sc);
            vb = (vb & 0x80000000u) ? ~vb : (vb | 0x80000000u);  // orderable
            key = ((unsigned long long)vb << 32) | (unsigned)(K2SZ - 1 - t);
        }
        keys[t] = key;
    }

    for (unsigned k = 2; k <= K2SZ; k <<= 1) {
        for (unsigned j = k >> 1; j > 0; j >>= 1) {
            __syncthreads();
            for (unsigned i = tid; i < K2SZ; i += BTHREADS) {
                unsigned ixj = i ^ j;
                if (ixj > i) {
                    unsigned long long a = keys[i], c = keys[ixj];
                    bool sw = ((i & k) == 0) ? (a < c) : (a > c);
                    if (sw) { keys[i] = c; keys[ixj] = a; }
                }
            }
        }
    }
    __syncthreads();

    if (tid < DETS) {
        unsigned long long key = keys[tid];
        unsigned vb = (unsigned)(key >> 32);
        float val = __uint_as_float((vb & 0x80000000u) ? (vb & 0x7FFFFFFFu) : ~vb);
        bool vld = val > 0.0f;
        float4 bx = make_float4(0.f, 0.f, 0.f, 0.f);
        float th = 0.f, lab = 0.f, scv = 0.f;
        if (vld) {
            int slot = K2SZ - 1 - (int)(key & 0xFFFFFFFFull);  // clsfg*DETS + cidx
            size_t g = (size_t)b * M + slot;
            bx  = ((const float4*)cBox)[g];
            th  = cTheta[g];
            lab = (float)(slot / DETS + 1);
            scv = val;
        }
        int o = b * DETS + tid;
        out[o * 4 + 0] = bx.x;
        out[o * 4 + 1] = bx.y;
        out[o * 4 + 2] = bx.z;
        out[o * 4 + 3] = bx.w;
        out[NB * DETS * 4 + o] = scv;
        out[NB * DETS * 5 + o] = th;
        out[NB * DETS * 6 + o] = lab;
        out[NB * DETS * 7 + o] = vld ? 1.0f : 0.0f;
    }
}

extern "C" void kernel_launch(void* const* d_in, const int* in_sizes, int n_in,
                              void* d_out, int out_size, void* d_ws, size_t ws_size,
                              hipStream_t stream) {
    const float* logits = (const float*)d_in[0];   // [2,2048,16]
    const float* deltas = (const float*)d_in[1];   // [2,2048,80]
    const float* props  = (const float*)d_in[2];   // [2,2048,4]
    float* out = (float*)d_out;                    // 1600 floats
    float* ws  = (float*)d_ws;

    float* boxAll   = ws;                                    // NPAIR*NN*4 (16B-aligned)
    float* scoreAll = boxAll   + (size_t)NPAIR * NN * 4;     // NPAIR*NN
    float* thetaAll = scoreAll + (size_t)NPAIR * NN;         // NPAIR*NN
    float* cBox     = thetaAll + (size_t)NPAIR * NN;         // NPAIR*DETS*4 (16B-aligned)
    float* cScore   = cBox     + (size_t)NPAIR * DETS * 4;   // NPAIR*DETS
    float* cTheta   = cScore   + (size_t)NPAIR * DETS;       // NPAIR*DETS

    hipLaunchKernelGGL(decode_kernel, dim3(NB * NN / 64), dim3(64), 0, stream,
                       logits, deltas, props, scoreAll, boxAll, thetaAll);
    hipLaunchKernelGGL(nms_kernel, dim3(NPAIR), dim3(BTHREADS), 0, stream,
                       scoreAll, boxAll, thetaAll, cScore, cBox, cTheta);
    hipLaunchKernelGGL(topk_kernel, dim3(NB), dim3(BTHREADS), 0, stream,
                       cScore, cBox, cTheta, out);
}

// Round 7
// 228.393 us; speedup vs baseline: 15.6325x; 1.2625x over previous
//
#include <hip/hip_runtime.h>

#define NB 2
#define NN 2048
#define NC 16
#define NFG 15
#define NPAIR (NB * NFG)
#define DETS 100
#define TH1 512
#define TH2 1024
#define SCORE_TH 0.05f
#define NMS_TH 0.5f
#define BBOX_CLIP 4.135166556742356f
#define IMG_MAX 1023.0f

// -------- Kernel 1: per (image,class) softmax + sort + decode + all-wave NMS + compaction ----
__global__ __launch_bounds__(TH1)
void nms_kernel(const float* __restrict__ logits,
                const float* __restrict__ deltas,
                const float* __restrict__ props,
                float* __restrict__ cScore,  // [NPAIR][DETS] (-1 pad)
                float* __restrict__ cBox,    // [NPAIR][DETS][4]
                float* __restrict__ cTheta)  // [NPAIR][DETS]
{
    const int pair = blockIdx.x;       // 0..29
    const int b    = pair / NFG;
    const int cls  = pair % NFG + 1;   // foreground class 1..15
    const int tid  = threadIdx.x;
    const int lane = tid & 63;

    const float* L = logits + (size_t)b * NN * NC;
    const float* D = deltas + (size_t)b * NN * NC * 5;
    const float* P = props  + (size_t)b * NN * 4;

    __shared__ unsigned long long keys[NN];     // 16 KB (intact after sort)
    __shared__ float4 sbl[NN];                  // 32 KB sorted boxes
    __shared__ unsigned long long remW[NN/64];  // 256 B remaining-candidate bitmask
    __shared__ int keptPos[DETS];               // 400 B   (total ~48.8 KB)

    // ---- Phase A: softmax score for this class (same op order as prior passing kernels) ----
    for (int n = tid; n < NN; n += TH1) {
        const float* lr = L + n * NC;
        float l[NC];
#pragma unroll
        for (int t = 0; t < NC / 4; ++t) {
            float4 v = ((const float4*)lr)[t];
            l[4*t+0] = v.x; l[4*t+1] = v.y; l[4*t+2] = v.z; l[4*t+3] = v.w;
        }
        float m = l[0];
#pragma unroll
        for (int c = 1; c < NC; ++c) m = fmaxf(m, l[c]);
        float sum = 0.0f, ec = 0.0f;
#pragma unroll
        for (int c = 0; c < NC; ++c) {
            float e = expf(__fsub_rn(l[c], m));
            sum = __fadd_rn(sum, e);
            if (c == cls) ec = e;
        }
        float sc = __fdiv_rn(ec, sum);
        // stable-descending key: positive-score bits | inverted index
        keys[n] = ((unsigned long long)__float_as_uint(sc) << 32)
                | (unsigned)(NN - 1 - n);
    }

    // ---- bitonic sort, descending (stable argsort(-scores)) ----
    for (unsigned k = 2; k <= NN; k <<= 1) {
        for (unsigned j = k >> 1; j > 0; j >>= 1) {
            __syncthreads();
            for (unsigned i = tid; i < NN; i += TH1) {
                unsigned ixj = i ^ j;
                if (ixj > i) {
                    unsigned long long a = keys[i], c = keys[ixj];
                    bool sw = ((i & k) == 0) ? (a < c) : (a > c);
                    if (sw) { keys[i] = c; keys[ixj] = a; }
                }
            }
        }
    }
    __syncthreads();

    // ---- Phase B: decode boxes straight into sorted slots + valid bitmask ----
    for (int n = tid; n < NN; n += TH1) {
        unsigned long long key = keys[n];
        int orig = NN - 1 - (int)(key & 0xFFFFFFFFull);

        float4 pv = ((const float4*)P)[orig];
        float w  = __fadd_rn(__fsub_rn(pv.z, pv.x), 1.0f);
        float h  = __fadd_rn(__fsub_rn(pv.w, pv.y), 1.0f);
        float cx = __fadd_rn(pv.x, __fmul_rn(0.5f, w));
        float cy = __fadd_rn(pv.y, __fmul_rn(0.5f, h));

        const float* dd = D + (size_t)orig * NC * 5 + cls * 5;
        float dx = __fdiv_rn(dd[0], 10.0f);
        float dy = __fdiv_rn(dd[1], 10.0f);
        float dw = fminf(__fdiv_rn(dd[2], 5.0f), BBOX_CLIP);
        float dh = fminf(__fdiv_rn(dd[3], 5.0f), BBOX_CLIP);

        float pcx = __fadd_rn(__fmul_rn(dx, w), cx);
        float pcy = __fadd_rn(__fmul_rn(dy, h), cy);
        float pw  = __fmul_rn(expf(dw), w);
        float ph  = __fmul_rn(expf(dh), h);

        float bx1 = __fsub_rn(pcx, __fmul_rn(0.5f, pw));
        float by1 = __fsub_rn(pcy, __fmul_rn(0.5f, ph));
        float bx2 = __fsub_rn(__fadd_rn(pcx, __fmul_rn(0.5f, pw)), 1.0f);
        float by2 = __fsub_rn(__fadd_rn(pcy, __fmul_rn(0.5f, ph)), 1.0f);

        bx1 = fminf(fmaxf(bx1, 0.0f), IMG_MAX);
        by1 = fminf(fmaxf(by1, 0.0f), IMG_MAX);
        bx2 = fminf(fmaxf(bx2, 0.0f), IMG_MAX);
        by2 = fminf(fmaxf(by2, 0.0f), IMG_MAX);

        sbl[n] = make_float4(bx1, by1, bx2, by2);

        float sc = __uint_as_float((unsigned)(key >> 32));
        unsigned long long bm = __ballot(sc > SCORE_TH);
        if (lane == 0) remW[n >> 6] = bm;   // n strided by 512: word-aligned per wave
    }
    __syncthreads();

    // ---- Phase C: all-wave NMS, 2 barriers per kept box (read-phase / write-phase) ----
    int kept = 0;
    while (kept < DETS) {
        // READ phase: every wave redundantly finds the next keep from the same
        // post-barrier remW state (no writes until the barrier below).
        unsigned long long mine = (lane < NN / 64) ? remW[lane] : 0ull;
        unsigned long long has = __ballot(mine != 0ull);
        if (has == 0ull) break;                       // uniform across all waves
        int fw = (int)__builtin_ctzll(has);
        unsigned lo = (unsigned)__shfl((int)(unsigned)mine, fw);
        unsigned hi = (unsigned)__shfl((int)(unsigned)(mine >> 32), fw);
        unsigned long long w64 = ((unsigned long long)hi << 32) | lo;
        int i = (fw << 6) + (int)__builtin_ctzll(w64);
        if (tid == 0) keptPos[kept] = i;
        ++kept;
        __syncthreads();   // all find-next reads complete before any suppression write

        // WRITE phase: suppression
        float4 a = sbl[i];                            // LDS broadcast
        float aarea = __fmul_rn(__fadd_rn(__fsub_rn(a.z, a.x), 1.0f),
                                __fadd_rn(__fsub_rn(a.w, a.y), 1.0f));
#pragma unroll
        for (int k = 0; k < NN / TH1; ++k) {          // 4 boxes per thread
            int j = k * TH1 + tid;
            float4 c = sbl[j];
            float xx1 = fmaxf(a.x, c.x);
            float yy1 = fmaxf(a.y, c.y);
            float xx2 = fminf(a.z, c.z);
            float yy2 = fminf(a.w, c.w);
            float iw = fmaxf(__fadd_rn(__fsub_rn(xx2, xx1), 1.0f), 0.0f);
            float ih = fmaxf(__fadd_rn(__fsub_rn(yy2, yy1), 1.0f), 0.0f);
            float inter = __fmul_rn(iw, ih);
            float carea = __fmul_rn(__fadd_rn(__fsub_rn(c.z, c.x), 1.0f),
                                    __fadd_rn(__fsub_rn(c.w, c.y), 1.0f));
            float denom = __fsub_rn(__fadd_rn(aarea, carea), inter);
            float iou = __fdiv_rn(inter, denom);
            unsigned long long bm = __ballot(iou > NMS_TH);
            // wave (tid>>6) exclusively owns word k*8 + (tid>>6); self-IoU clears bit i
            if (lane == 0) remW[k * (TH1/64) + (tid >> 6)] &= ~bm;
        }
        __syncthreads();   // all suppression writes visible before next find-next
    }
    __syncthreads();

    // ---- Phase D: compact first <=100 kept (exact per-pair top-100; kept is uniform) ----
    if (tid < DETS) {
        float sc = -1.0f, th = 0.0f;
        float4 bx = make_float4(0.f, 0.f, 0.f, 0.f);
        if (tid < kept) {
            int p = keptPos[tid];
            unsigned long long key = keys[p];
            sc = __uint_as_float((unsigned)(key >> 32));
            bx = sbl[p];
            int orig = NN - 1 - (int)(key & 0xFFFFFFFFull);
            th = D[(size_t)orig * NC * 5 + cls * 5 + 4];
        }
        int g = pair * DETS + tid;
        cScore[g] = sc;
        cTheta[g] = th;
        ((float4*)cBox)[g] = bx;
    }
}

// -------- Kernel 2: per-image top-100 over 1500 compacted candidates --------
#define K2SZ 2048
__global__ __launch_bounds__(TH2)
void topk_kernel(const float* __restrict__ cScore,
                 const float* __restrict__ cBox,
                 const float* __restrict__ cTheta,
                 float* __restrict__ out)
{
    const int b   = blockIdx.x;
    const int tid = threadIdx.x;
    const int M   = NFG * DETS;   // 1500

    __shared__ unsigned long long keys[K2SZ];   // 16 KB

    for (int t = tid; t < K2SZ; t += TH2) {
        unsigned long long key = 0ull;          // padding sorts last
        if (t < M) {
            float sc = cScore[(size_t)b * M + t];
            unsigned vb = __float_as_uint(sc);
            vb = (vb & 0x80000000u) ? ~vb : (vb | 0x80000000u);  // orderable
            key = ((unsigned long long)vb << 32) | (unsigned)(K2SZ - 1 - t);
        }
        keys[t] = key;
    }

    for (unsigned k = 2; k <= K2SZ; k <<= 1) {
        for (unsigned j = k >> 1; j > 0; j >>= 1) {
            __syncthreads();
            for (unsigned i = tid; i < K2SZ; i += TH2) {
                unsigned ixj = i ^ j;
                if (ixj > i) {
                    unsigned long long a = keys[i], c = keys[ixj];
                    bool sw = ((i & k) == 0) ? (a < c) : (a > c);
                    if (sw) { keys[i] = c; keys[ixj] = a; }
                }
            }
        }
    }
    __syncthreads();

    if (tid < DETS) {
        unsigned long long key = keys[tid];
        unsigned vb = (unsigned)(key >> 32);
        float val = __uint_as_float((vb & 0x80000000u) ? (vb & 0x7FFFFFFFu) : ~vb);
        bool vld = val > 0.0f;
        float4 bx = make_float4(0.f, 0.f, 0.f, 0.f);
        float th = 0.f, lab = 0.f, scv = 0.f;
        if (vld) {
            int slot = K2SZ - 1 - (int)(key & 0xFFFFFFFFull);  // clsfg*DETS + cidx
            size_t g = (size_t)b * M + slot;
            bx  = ((const float4*)cBox)[g];
            th  = cTheta[g];
            lab = (float)(slot / DETS + 1);
            scv = val;
        }
        int o = b * DETS + tid;
        // output: boxes[2][100][4] | scores[2][100] | theta[2][100] | labels[2][100] | valid[2][100]
        out[o * 4 + 0] = bx.x;
        out[o * 4 + 1] = bx.y;
        out[o * 4 + 2] = bx.z;
        out[o * 4 + 3] = bx.w;
        out[NB * DETS * 4 + o] = scv;
        out[NB * DETS * 5 + o] = th;
        out[NB * DETS * 6 + o] = lab;
        out[NB * DETS * 7 + o] = vld ? 1.0f : 0.0f;
    }
}

extern "C" void kernel_launch(void* const* d_in, const int* in_sizes, int n_in,
                              void* d_out, int out_size, void* d_ws, size_t ws_size,
                              hipStream_t stream) {
    const float* logits = (const float*)d_in[0];   // [2,2048,16]
    const float* deltas = (const float*)d_in[1];   // [2,2048,80]
    const float* props  = (const float*)d_in[2];   // [2,2048,4]
    float* out = (float*)d_out;                    // 1600 floats
    float* ws  = (float*)d_ws;

    float* cBox   = ws;                                   // NPAIR*DETS*4 (16B-aligned)
    float* cScore = cBox   + (size_t)NPAIR * DETS * 4;    // NPAIR*DETS
    float* cTheta = cScore + (size_t)NPAIR * DETS;        // NPAIR*DETS

    hipLaunchKernelGGL(nms_kernel, dim3(NPAIR), dim3(TH1), 0, stream,
                       logits, deltas, props, cScore, cBox, cTheta);
    hipLaunchKernelGGL(topk_kernel, dim3(NB), dim3(TH2), 0, stream,
                       cScore, cBox, cTheta, out);
}

// Round 8
// 165.145 us; speedup vs baseline: 21.6196x; 1.3830x over previous
//
#include <hip/hip_runtime.h>

#define NB 2
#define NN 2048
#define NC 16
#define NFG 15
#define NPAIR (NB * NFG)
#define DETS 100
#define TH1 512
#define TH2 1024
#define TKEEP 256
#define SCORE_TH 0.05f
#define NMS_TH 0.5f
#define BBOX_CLIP 4.135166556742356f
#define IMG_MAX 1023.0f

__device__ __forceinline__ float iou_box(float4 a, float aarea, float4 c) {
    float xx1 = fmaxf(a.x, c.x);
    float yy1 = fmaxf(a.y, c.y);
    float xx2 = fminf(a.z, c.z);
    float yy2 = fminf(a.w, c.w);
    float iw = fmaxf(__fadd_rn(__fsub_rn(xx2, xx1), 1.0f), 0.0f);
    float ih = fmaxf(__fadd_rn(__fsub_rn(yy2, yy1), 1.0f), 0.0f);
    float inter = __fmul_rn(iw, ih);
    float carea = __fmul_rn(__fadd_rn(__fsub_rn(c.z, c.x), 1.0f),
                            __fadd_rn(__fsub_rn(c.w, c.y), 1.0f));
    float denom = __fsub_rn(__fadd_rn(aarea, carea), inter);
    return __fdiv_rn(inter, denom);
}

// -------- Kernel 1: per (image,class) softmax + sort + decode + matrix-NMS + compaction ----
__global__ __launch_bounds__(TH1)
void nms_kernel(const float* __restrict__ logits,
                const float* __restrict__ deltas,
                const float* __restrict__ props,
                float* __restrict__ cScore,  // [NPAIR][DETS] (-1 pad)
                float* __restrict__ cBox,    // [NPAIR][DETS][4]
                float* __restrict__ cTheta)  // [NPAIR][DETS]
{
    const int pair = blockIdx.x;       // 0..29
    const int b    = pair / NFG;
    const int cls  = pair % NFG + 1;   // foreground class 1..15
    const int tid  = threadIdx.x;
    const int lane = tid & 63;

    const float* L = logits + (size_t)b * NN * NC;
    const float* D = deltas + (size_t)b * NN * NC * 5;
    const float* P = props  + (size_t)b * NN * 4;

    __shared__ unsigned long long keys[NN];          // 16 KB (intact after sort)
    __shared__ float4 sbl[NN];                       // 32 KB sorted boxes
    __shared__ unsigned long long supmat[TKEEP][4];  //  8 KB suppression matrix
    __shared__ unsigned long long remW[NN/64];       // 256 B remaining-candidate bitmask
    __shared__ int keptPos[DETS];                    // 400 B
    __shared__ int keptCnt;

    // ---- Phase A: softmax score for this class ----
    for (int n = tid; n < NN; n += TH1) {
        const float* lr = L + n * NC;
        float l[NC];
#pragma unroll
        for (int t = 0; t < NC / 4; ++t) {
            float4 v = ((const float4*)lr)[t];
            l[4*t+0] = v.x; l[4*t+1] = v.y; l[4*t+2] = v.z; l[4*t+3] = v.w;
        }
        float m = l[0];
#pragma unroll
        for (int c = 1; c < NC; ++c) m = fmaxf(m, l[c]);
        float sum = 0.0f, ec = 0.0f;
#pragma unroll
        for (int c = 0; c < NC; ++c) {
            float e = expf(__fsub_rn(l[c], m));
            sum = __fadd_rn(sum, e);
            if (c == cls) ec = e;
        }
        float sc = __fdiv_rn(ec, sum);
        keys[n] = ((unsigned long long)__float_as_uint(sc) << 32)
                | (unsigned)(NN - 1 - n);
    }

    // ---- bitonic sort, descending (stable argsort(-scores)) ----
    for (unsigned k = 2; k <= NN; k <<= 1) {
        for (unsigned j = k >> 1; j > 0; j >>= 1) {
            __syncthreads();
            for (unsigned i = tid; i < NN; i += TH1) {
                unsigned ixj = i ^ j;
                if (ixj > i) {
                    unsigned long long a = keys[i], c = keys[ixj];
                    bool sw = ((i & k) == 0) ? (a < c) : (a > c);
                    if (sw) { keys[i] = c; keys[ixj] = a; }
                }
            }
        }
    }
    __syncthreads();

    // ---- Phase B: decode boxes straight into sorted slots + valid bitmask ----
    for (int n = tid; n < NN; n += TH1) {
        unsigned long long key = keys[n];
        int orig = NN - 1 - (int)(key & 0xFFFFFFFFull);

        float4 pv = ((const float4*)P)[orig];
        float w  = __fadd_rn(__fsub_rn(pv.z, pv.x), 1.0f);
        float h  = __fadd_rn(__fsub_rn(pv.w, pv.y), 1.0f);
        float cx = __fadd_rn(pv.x, __fmul_rn(0.5f, w));
        float cy = __fadd_rn(pv.y, __fmul_rn(0.5f, h));

        const float* dd = D + (size_t)orig * NC * 5 + cls * 5;
        float dx = __fdiv_rn(dd[0], 10.0f);
        float dy = __fdiv_rn(dd[1], 10.0f);
        float dw = fminf(__fdiv_rn(dd[2], 5.0f), BBOX_CLIP);
        float dh = fminf(__fdiv_rn(dd[3], 5.0f), BBOX_CLIP);

        float pcx = __fadd_rn(__fmul_rn(dx, w), cx);
        float pcy = __fadd_rn(__fmul_rn(dy, h), cy);
        float pw  = __fmul_rn(expf(dw), w);
        float ph  = __fmul_rn(expf(dh), h);

        float bx1 = __fsub_rn(pcx, __fmul_rn(0.5f, pw));
        float by1 = __fsub_rn(pcy, __fmul_rn(0.5f, ph));
        float bx2 = __fsub_rn(__fadd_rn(pcx, __fmul_rn(0.5f, pw)), 1.0f);
        float by2 = __fsub_rn(__fadd_rn(pcy, __fmul_rn(0.5f, ph)), 1.0f);

        bx1 = fminf(fmaxf(bx1, 0.0f), IMG_MAX);
        by1 = fminf(fmaxf(by1, 0.0f), IMG_MAX);
        bx2 = fminf(fmaxf(bx2, 0.0f), IMG_MAX);
        by2 = fminf(fmaxf(by2, 0.0f), IMG_MAX);

        sbl[n] = make_float4(bx1, by1, bx2, by2);

        float sc = __uint_as_float((unsigned)(key >> 32));
        unsigned long long bm = __ballot(sc > SCORE_TH);
        if (lane == 0) remW[n >> 6] = bm;   // n strided by 512: word-aligned per wave
    }
    __syncthreads();

    // ---- Phase C1: suppression matrix over top TKEEP candidates ----
    for (int t = tid; t < TKEEP * 4; t += TH1) {
        int i = t >> 2, w = t & 3;
        float4 a = sbl[i];
        float aarea = __fmul_rn(__fadd_rn(__fsub_rn(a.z, a.x), 1.0f),
                                __fadd_rn(__fsub_rn(a.w, a.y), 1.0f));
        unsigned long long m = 0ull;
#pragma unroll 8
        for (int l = 0; l < 64; ++l) {
            float iou = iou_box(a, aarea, sbl[(w << 6) + l]);
            if (iou > NMS_TH) m |= (1ull << l);
        }
        supmat[i][w] = m;
    }
    __syncthreads();

    // ---- Phase C2: single-wave barrier-free greedy resolve over first TKEEP ----
    if (tid < 64) {
        unsigned long long rem = (lane < TKEEP / 64) ? remW[lane] : 0ull;
        int kept = 0;
        while (kept < DETS) {
            unsigned long long has = __ballot(rem != 0ull);
            if (has == 0ull) break;
            int fw = (int)__builtin_ctzll(has);
            unsigned lo = (unsigned)__shfl((int)(unsigned)rem, fw);
            unsigned hi = (unsigned)__shfl((int)(unsigned)(rem >> 32), fw);
            unsigned long long w64 = ((unsigned long long)hi << 32) | lo;
            int i = (fw << 6) + (int)__builtin_ctzll(w64);
            if (lane == 0) keptPos[kept] = i;
            ++kept;
            if (lane < TKEEP / 64) rem &= ~supmat[i][lane];   // self-bit cleared (IoU=1)
        }
        if (lane == 0) keptCnt = kept;
    }
    __syncthreads();

    // ---- Phase C3: fallback if TKEEP was insufficient (exact; never triggers here) ----
    int keptNow = keptCnt;
    if (keptNow < DETS) {
        if (tid < TKEEP / 64) remW[tid] = 0ull;   // first TKEEP positions fully processed
        __syncthreads();
        // bulk-suppress tail by all kept boxes
        for (int k = 0; k < NN / TH1; ++k) {
            int j = k * TH1 + tid;
            bool sup = false;
            if (j >= TKEEP) {
                float4 c = sbl[j];
                for (int q = 0; q < keptNow; ++q) {
                    float4 a = sbl[keptPos[q]];
                    float aarea = __fmul_rn(__fadd_rn(__fsub_rn(a.z, a.x), 1.0f),
                                            __fadd_rn(__fsub_rn(a.w, a.y), 1.0f));
                    sup = sup || (iou_box(a, aarea, c) > NMS_TH);
                }
            }
            unsigned long long bm = __ballot(sup);
            if (lane == 0) remW[k * (TH1/64) + (tid >> 6)] &= ~bm;
        }
        __syncthreads();
        // two-barrier greedy loop over the remainder (round-7 structure)
        int kept = keptNow;
        while (kept < DETS) {
            unsigned long long mine = (lane < NN / 64) ? remW[lane] : 0ull;
            unsigned long long has = __ballot(mine != 0ull);
            if (has == 0ull) break;
            int fw = (int)__builtin_ctzll(has);
            unsigned lo = (unsigned)__shfl((int)(unsigned)mine, fw);
            unsigned hi = (unsigned)__shfl((int)(unsigned)(mine >> 32), fw);
            unsigned long long w64 = ((unsigned long long)hi << 32) | lo;
            int i = (fw << 6) + (int)__builtin_ctzll(w64);
            if (tid == 0) keptPos[kept] = i;
            ++kept;
            __syncthreads();
            float4 a = sbl[i];
            float aarea = __fmul_rn(__fadd_rn(__fsub_rn(a.z, a.x), 1.0f),
                                    __fadd_rn(__fsub_rn(a.w, a.y), 1.0f));
#pragma unroll
            for (int k = 0; k < NN / TH1; ++k) {
                int j = k * TH1 + tid;
                float iou = iou_box(a, aarea, sbl[j]);
                unsigned long long bm = __ballot(iou > NMS_TH);
                if (lane == 0) remW[k * (TH1/64) + (tid >> 6)] &= ~bm;
            }
            __syncthreads();
        }
        if (tid == 0) keptCnt = kept;
        __syncthreads();
    }

    // ---- Phase D: compact first <=100 kept (exact per-pair top-100) ----
    if (tid < DETS) {
        int kc = keptCnt;
        float sc = -1.0f, th = 0.0f;
        float4 bx = make_float4(0.f, 0.f, 0.f, 0.f);
        if (tid < kc) {
            int p = keptPos[tid];
            unsigned long long key = keys[p];
            sc = __uint_as_float((unsigned)(key >> 32));
            bx = sbl[p];
            int orig = NN - 1 - (int)(key & 0xFFFFFFFFull);
            th = D[(size_t)orig * NC * 5 + cls * 5 + 4];
        }
        int g = pair * DETS + tid;
        cScore[g] = sc;
        cTheta[g] = th;
        ((float4*)cBox)[g] = bx;
    }
}

// -------- Kernel 2: per-image top-100 over 1500 compacted candidates --------
#define K2SZ 2048
__global__ __launch_bounds__(TH2)
void topk_kernel(const float* __restrict__ cScore,
                 const float* __restrict__ cBox,
                 const float* __restrict__ cTheta,
                 float* __restrict__ out)
{
    const int b   = blockIdx.x;
    const int tid = threadIdx.x;
    const int M   = NFG * DETS;   // 1500

    __shared__ unsigned long long keys[K2SZ];   // 16 KB

    for (int t = tid; t < K2SZ; t += TH2) {
        unsigned long long key = 0ull;          // padding sorts last
        if (t < M) {
            float sc = cScore[(size_t)b * M + t];
            unsigned vb = __float_as_uint(sc);
            vb = (vb & 0x80000000u) ? ~vb : (vb | 0x80000000u);  // orderable
            key = ((unsigned long long)vb << 32) | (unsigned)(K2SZ - 1 - t);
        }
        keys[t] = key;
    }

    for (unsigned k = 2; k <= K2SZ; k <<= 1) {
        for (unsigned j = k >> 1; j > 0; j >>= 1) {
            __syncthreads();
            for (unsigned i = tid; i < K2SZ; i += TH2) {
                unsigned ixj = i ^ j;
                if (ixj > i) {
                    unsigned long long a = keys[i], c = keys[ixj];
                    bool sw = ((i & k) == 0) ? (a < c) : (a > c);
                    if (sw) { keys[i] = c; keys[ixj] = a; }
                }
            }
        }
    }
    __syncthreads();

    if (tid < DETS) {
        unsigned long long key = keys[tid];
        unsigned vb = (unsigned)(key >> 32);
        float val = __uint_as_float((vb & 0x80000000u) ? (vb & 0x7FFFFFFFu) : ~vb);
        bool vld = val > 0.0f;
        float4 bx = make_float4(0.f, 0.f, 0.f, 0.f);
        float th = 0.f, lab = 0.f, scv = 0.f;
        if (vld) {
            int slot = K2SZ - 1 - (int)(key & 0xFFFFFFFFull);  // clsfg*DETS + cidx
            size_t g = (size_t)b * M + slot;
            bx  = ((const float4*)cBox)[g];
            th  = cTheta[g];
            lab = (float)(slot / DETS + 1);
            scv = val;
        }
        int o = b * DETS + tid;
        // output: boxes[2][100][4] | scores[2][100] | theta[2][100] | labels[2][100] | valid[2][100]
        out[o * 4 + 0] = bx.x;
        out[o * 4 + 1] = bx.y;
        out[o * 4 + 2] = bx.z;
        out[o * 4 + 3] = bx.w;
        out[NB * DETS * 4 + o] = scv;
        out[NB * DETS * 5 + o] = th;
        out[NB * DETS * 6 + o] = lab;
        out[NB * DETS * 7 + o] = vld ? 1.0f : 0.0f;
    }
}

extern "C" void kernel_launch(void* const* d_in, const int* in_sizes, int n_in,
                              void* d_out, int out_size, void* d_ws, size_t ws_size,
                              hipStream_t stream) {
    const float* logits = (const float*)d_in[0];   // [2,2048,16]
    const float* deltas = (const float*)d_in[1];   // [2,2048,80]
    const float* props  = (const float*)d_in[2];   // [2,2048,4]
    float* out = (float*)d_out;                    // 1600 floats
    float* ws  = (float*)d_ws;

    float* cBox   = ws;                                   // NPAIR*DETS*4 (16B-aligned)
    float* cScore = cBox   + (size_t)NPAIR * DETS * 4;    // NPAIR*DETS
    float* cTheta = cScore + (size_t)NPAIR * DETS;        // NPAIR*DETS

    hipLaunchKernelGGL(nms_kernel, dim3(NPAIR), dim3(TH1), 0, stream,
                       logits, deltas, props, cScore, cBox, cTheta);
    hipLaunchKernelGGL(topk_kernel, dim3(NB), dim3(TH2), 0, stream,
                       cScore, cBox, cTheta, out);
}